// Round 10
// baseline (1625.920 us; speedup 1.0000x reference)
//
#include <hip/hip_runtime.h>
#include <hip/hip_bf16.h>
#include <cmath>

// B=4, N=1024, DIM=1024, H=16, DH=64, M=16, QK_SCALE=10
typedef __attribute__((ext_vector_type(8))) short short8;
typedef __attribute__((ext_vector_type(4))) float f32x4;

__device__ __forceinline__ unsigned short to_bf(float f) {
  __hip_bfloat16 h = __float2bfloat16(f);
  return __builtin_bit_cast(unsigned short, h);
}

// -------- fp32 -> bf16 elementwise ------------------------------------------
__global__ __launch_bounds__(256)
void cvt_bf16x4(const float* __restrict__ in, unsigned short* __restrict__ out, int n4)
{
  int i = blockIdx.x * 256 + threadIdx.x;
  if (i < n4) {
    float4 v = ((const float4*)in)[i];
    ushort4 o;
    o.x = to_bf(v.x); o.y = to_bf(v.y); o.z = to_bf(v.z); o.w = to_bf(v.w);
    ((ushort4*)out)[i] = o;
  }
}

// -------- W [1024 k][1024 n] fp32 -> WT [n][k] bf16 -------------------------
__global__ __launch_bounds__(256)
void transpose_to_bf(const float* __restrict__ W, unsigned short* __restrict__ WT)
{
  __shared__ float tile[64][65];
  const int n0 = blockIdx.x * 64, k0 = blockIdx.y * 64;
  const int t = threadIdx.x, c = t & 63, r4 = t >> 6;
#pragma unroll
  for (int q = 0; q < 16; ++q) {
    int r = (q << 2) + r4;
    tile[r][c] = W[(size_t)(k0 + r) * 1024 + n0 + c];
  }
  __syncthreads();
#pragma unroll
  for (int q = 0; q < 16; ++q) {
    int r = (q << 2) + r4;
    WT[(size_t)(n0 + r) * 1024 + k0 + c] = to_bf(tile[c][r]);
  }
}

// ---- bf16 MFMA GEMM, 128x128 tile, BK=32, stride-80 LDS, reg double-buffer -
// mode 0: fp32 C; mode 1: bf16 V^T into vallT[b][n][16+nn];
// mode 2: fp32 C = sigmoid(acc + bias2[n])
__global__ __launch_bounds__(256)
void gemm_bf128(const unsigned short* __restrict__ A, const unsigned short* __restrict__ BT,
                float* __restrict__ C, unsigned short* __restrict__ Vout,
                const float* __restrict__ bias2, int mode)
{
  __shared__ __align__(16) unsigned short Ab[128 * 40];
  __shared__ __align__(16) unsigned short Bb[128 * 40];
  const int t = threadIdx.x, lane = t & 63, w = t >> 6;
  const int m = lane & 15, quad = lane >> 4;
  const int wm = w & 1, wn = w >> 1;
  const int row0 = blockIdx.y << 7, col0 = blockIdx.x << 7;

  const int c0 = t,        r0 = c0 >> 2, kp0 = c0 & 3;
  const int c1 = t + 256,  r1 = c1 >> 2, kp1 = c1 & 3;

  f32x4 acc[4][4];
#pragma unroll
  for (int mi = 0; mi < 4; ++mi)
#pragma unroll
    for (int ni = 0; ni < 4; ++ni) acc[mi][ni] = (f32x4){0.f, 0.f, 0.f, 0.f};

  // prefetch k-tile 0
  uint4 pa0 = *(const uint4*)(A + (size_t)(row0 + r0) * 1024 + kp0 * 8);
  uint4 pa1 = *(const uint4*)(A + (size_t)(row0 + r1) * 1024 + kp1 * 8);
  uint4 pb0 = *(const uint4*)(BT + (size_t)(col0 + r0) * 1024 + kp0 * 8);
  uint4 pb1 = *(const uint4*)(BT + (size_t)(col0 + r1) * 1024 + kp1 * 8);

  for (int kk = 0; kk < 1024; kk += 32) {
    *(uint4*)((char*)Ab + r0 * 80 + kp0 * 16) = pa0;
    *(uint4*)((char*)Ab + r1 * 80 + kp1 * 16) = pa1;
    *(uint4*)((char*)Bb + r0 * 80 + kp0 * 16) = pb0;
    *(uint4*)((char*)Bb + r1 * 80 + kp1 * 16) = pb1;
    __syncthreads();
    if (kk + 32 < 1024) {      // next tile loads overlap the MFMA phase below
      pa0 = *(const uint4*)(A + (size_t)(row0 + r0) * 1024 + kk + 32 + kp0 * 8);
      pa1 = *(const uint4*)(A + (size_t)(row0 + r1) * 1024 + kk + 32 + kp1 * 8);
      pb0 = *(const uint4*)(BT + (size_t)(col0 + r0) * 1024 + kk + 32 + kp0 * 8);
      pb1 = *(const uint4*)(BT + (size_t)(col0 + r1) * 1024 + kk + 32 + kp1 * 8);
    }
    short8 af[4], bf[4];
#pragma unroll
    for (int mi = 0; mi < 4; ++mi)
      af[mi] = *(const short8*)((char*)Ab + ((wm << 6) + (mi << 4) + m) * 80 + quad * 16);
#pragma unroll
    for (int ni = 0; ni < 4; ++ni)
      bf[ni] = *(const short8*)((char*)Bb + ((wn << 6) + (ni << 4) + m) * 80 + quad * 16);
#pragma unroll
    for (int mi = 0; mi < 4; ++mi)
#pragma unroll
      for (int ni = 0; ni < 4; ++ni)
        acc[mi][ni] = __builtin_amdgcn_mfma_f32_16x16x32_bf16(af[mi], bf[ni], acc[mi][ni], 0, 0, 0);
    __syncthreads();
  }
  // C/D layout: col = lane&15, row = quad*4 + reg
#pragma unroll
  for (int mi = 0; mi < 4; ++mi)
#pragma unroll
    for (int ni = 0; ni < 4; ++ni)
#pragma unroll
      for (int reg = 0; reg < 4; ++reg) {
        int mrow = row0 + (wm << 6) + (mi << 4) + (quad << 2) + reg;
        int ncol = col0 + (wn << 6) + (ni << 4) + m;
        float v = acc[mi][ni][reg];
        if (mode == 0) {
          C[((size_t)mrow << 10) + ncol] = v;
        } else if (mode == 2) {
          float s = v + bias2[ncol];
          C[((size_t)mrow << 10) + ncol] = 1.f / (1.f + __expf(-s));
        } else {
          int bb = mrow >> 10, nn = mrow & 1023;
          Vout[((size_t)((bb << 10) + ncol)) * 1056 + 16 + nn] = to_bf(v);
        }
      }
}

// ---- fused head-gate projection: hg = sigmoid(x @ W_hg + b_hg) -------------
__global__ __launch_bounds__(256)
void hgate_proj(const float* __restrict__ x, const float* __restrict__ W,
                const float* __restrict__ bias, float* __restrict__ hg)
{
  int G = blockIdx.x * 256 + threadIdx.x;
  int row = G >> 4, h = G & 15;
  const float4* x4 = (const float4*)(x + ((size_t)row << 10));
  float acc = 0.f;
#pragma unroll 4
  for (int k4 = 0; k4 < 256; ++k4) {
    float4 xv = x4[k4];
    int kb = k4 << 2;
    acc += xv.x * W[(kb + 0) * 16 + h] + xv.y * W[(kb + 1) * 16 + h]
         + xv.z * W[(kb + 2) * 16 + h] + xv.w * W[(kb + 3) * 16 + h];
  }
  float v = acc + bias[h];
  hg[(row << 4) + h] = 1.f / (1.f + __expf(-v));
}

// ------ q post: l2norm * scale * QK_SCALE + rope -> bf16 qb -----------------
__global__ __launch_bounds__(256)
void q_post_bf(const float* __restrict__ q_lin, const float* __restrict__ scale,
               const float* __restrict__ freqs, unsigned short* __restrict__ qb)
{
  int gid = blockIdx.x * 256 + threadIdx.x;
  int d = gid & 63;
  int row = gid >> 6;
  int h = row & 15;
  int n = (row >> 4) & 1023;
  float v = q_lin[gid];
  float ss = v * v;
#pragma unroll
  for (int off = 32; off; off >>= 1) ss += __shfl_xor(ss, off);
  v = v / fmaxf(sqrtf(ss), 1e-12f) * scale[(h << 6) + d];
  float f = freqs[(n << 6) + d];
  float other = __shfl_xor(v, 1);
  float rot = (d & 1) ? other : -other;
  qb[gid] = to_bf((v * cosf(f) + rot * sinf(f)) * 10.f);   // QK_SCALE folded
}

// ------ k post: l2norm*scale + rope, bf16 into kall (row stride 1056) -------
__global__ __launch_bounds__(256)
void k_post_bf(const float* __restrict__ k_lin, const float* __restrict__ scale,
               const float* __restrict__ freqs, unsigned short* __restrict__ kall)
{
  int gid = blockIdx.x * 256 + threadIdx.x;
  int d = gid & 63;
  int row = gid >> 6;
  int h = row & 15;
  int n = (row >> 4) & 1023;
  int b = row >> 14;
  float v = k_lin[gid];
  float ss = v * v;
#pragma unroll
  for (int off = 32; off; off >>= 1) ss += __shfl_xor(ss, off);
  v = v / fmaxf(sqrtf(ss), 1e-12f) * scale[(h << 6) + d];
  float f = freqs[(n << 6) + d];
  float other = __shfl_xor(v, 1);
  float rot = (d & 1) ? other : -other;
  float out = v * cosf(f) + rot * sinf(f);
  kall[(size_t)(b * 1056 + 16 + n) * 1024 + (h << 6) + d] = to_bf(out);
}

// ------ memory slots into kall rows 0..15 and vallT cols 0..15 --------------
__global__ __launch_bounds__(256)
void mem_build(const float* __restrict__ mem_k, const float* __restrict__ mem_v,
               const float* __restrict__ k_scale,
               unsigned short* __restrict__ kall, unsigned short* __restrict__ vallT)
{
  int gid = blockIdx.x * 256 + threadIdx.x;   // 16384 = H*M*64
  int d = gid & 63;
  int row = gid >> 6;            // h*M + mm
  int h = row >> 4, mm = row & 15;
  float v = mem_k[gid];
  float ss = v * v;
#pragma unroll
  for (int off = 32; off; off >>= 1) ss += __shfl_xor(ss, off);
  unsigned short kb = to_bf(v / fmaxf(sqrtf(ss), 1e-12f) * k_scale[(h << 6) + d]);
  unsigned short vb = to_bf(mem_v[gid]);
#pragma unroll
  for (int b = 0; b < 4; ++b) {
    kall[(size_t)(b * 1056 + mm) * 1024 + (h << 6) + d] = kb;
    vallT[(size_t)((b << 10) + (h << 6) + d) * 1056 + mm] = vb;
  }
}

// =========== two-pass MFMA attention, in-register head mixes ================
// Per 64-j macro-unit: wave w owns the 16-j subtile js=j0+16w and computes QK
// for ALL 16 heads -> all h-values for one (i,j) live in ONE lane
// (i=quad*4+reg, j=m). W_pre premix + exp (+ normalize + W_post in pass 2)
// are pure register math with packed f32x4 weight broadcasts. No sS.
// Macro-units: un(it) = (it+5)>>2, total 2240 over (b,it); flat-split.

// ---- pass 1: denominators L[b][i][g] via atomicAdd -------------------------
__global__ __launch_bounds__(256, 3)
void attn_lsum(const unsigned short* __restrict__ qb, const unsigned short* __restrict__ kall,
               const float* __restrict__ W_pre, float* __restrict__ Lbuf)
{
  __shared__ f32x4 sWpre4[64];
  const int t = threadIdx.x, lane = t & 63, w = t >> 6;
  const int m = lane & 15, quad = lane >> 4;
  if (t < 64) {
    int h = t >> 2, p4 = t & 3;
    sWpre4[t] = (f32x4){W_pre[(4 * p4 + 0) * 16 + h], W_pre[(4 * p4 + 1) * 16 + h],
                        W_pre[(4 * p4 + 2) * 16 + h], W_pre[(4 * p4 + 3) * 16 + h]};
  }
  __syncthreads();

  int u = 2 * blockIdx.x;          // grid 1120, 2 macro-units each
  const int u1 = u + 2;

  int accu = 0, bi = 0;
  while (true) {
    int un = ((bi & 63) + 5) >> 2;
    if (accu + un > u) break;
    accu += un; ++bi;
  }
  int b = bi >> 6, it = bi & 63, uoff = u - accu;

  f32x4 partL[4][4];               // [reg][p], components = e (g = 4p+e)
  bool fresh = true;

  for (; u < u1; ++u) {
    const int i0 = it << 4;
    if (fresh) {
#pragma unroll
      for (int r = 0; r < 4; ++r)
#pragma unroll
        for (int p = 0; p < 4; ++p) partL[r][p] = (f32x4){0.f, 0.f, 0.f, 0.f};
      fresh = false;
    }
    const int js = (uoff << 6) + (w << 4);
    if (js <= i0 + 31) {           // else: whole subtile causally masked
      const int jj = min(js + m, 1055);
      const unsigned short* qrow = qb + (((size_t)((b << 10) + i0 + m)) << 10);
      const unsigned short* krow = kall + (((size_t)(b * 1056 + jj)) << 10);
      f32x4 ap[4][4];
#pragma unroll
      for (int r = 0; r < 4; ++r)
#pragma unroll
        for (int p = 0; p < 4; ++p) ap[r][p] = (f32x4){0.f, 0.f, 0.f, 0.f};
#pragma unroll
      for (int h = 0; h < 16; ++h) {
        short8 q0 = *(const short8*)(qrow + h * 64 + quad * 8);
        short8 q1 = *(const short8*)(qrow + h * 64 + 32 + quad * 8);
        short8 k0 = *(const short8*)(krow + h * 64 + quad * 8);
        short8 k1 = *(const short8*)(krow + h * 64 + 32 + quad * 8);
        f32x4 acc = (f32x4){0.f, 0.f, 0.f, 0.f};
        acc = __builtin_amdgcn_mfma_f32_16x16x32_bf16(q0, k0, acc, 0, 0, 0);
        acc = __builtin_amdgcn_mfma_f32_16x16x32_bf16(q1, k1, acc, 0, 0, 0);
#pragma unroll
        for (int p = 0; p < 4; ++p) {
          f32x4 wv = sWpre4[(h << 2) + p];
#pragma unroll
          for (int r = 0; r < 4; ++r) ap[r][p] += wv * acc[r];
        }
      }
#pragma unroll
      for (int r = 0; r < 4; ++r) {
        const int iL = (quad << 2) + r;
        const bool ok = (js + m) <= (i0 + iL + 16);
#pragma unroll
        for (int p = 0; p < 4; ++p)
#pragma unroll
          for (int e = 0; e < 4; ++e)
            partL[r][p][e] += ok ? __expf(ap[r][p][e] - 20.f) : 0.f;
      }
    }
    ++uoff;
    if (uoff == ((it + 5) >> 2)) {
#pragma unroll
      for (int r = 0; r < 4; ++r)
#pragma unroll
        for (int p = 0; p < 4; ++p)
#pragma unroll
          for (int e = 0; e < 4; ++e) {
            float v = partL[r][p][e];
            v += __shfl_xor(v, 1); v += __shfl_xor(v, 2);
            v += __shfl_xor(v, 4); v += __shfl_xor(v, 8);
            if (m == 0)
              atomicAdd(&Lbuf[(((size_t)(b << 10) + i0 + (quad << 2) + r) << 4)
                              + (p << 2) + e], v);
          }
      ++bi; b = bi >> 6; it = bi & 63; uoff = 0; fresh = true;
    }
  }
  if (!fresh) {
    const int i0 = it << 4;
#pragma unroll
    for (int r = 0; r < 4; ++r)
#pragma unroll
      for (int p = 0; p < 4; ++p)
#pragma unroll
        for (int e = 0; e < 4; ++e) {
          float v = partL[r][p][e];
          v += __shfl_xor(v, 1); v += __shfl_xor(v, 2);
          v += __shfl_xor(v, 4); v += __shfl_xor(v, 8);
          if (m == 0)
            atomicAdd(&Lbuf[(((size_t)(b << 10) + i0 + (quad << 2) + r) << 4)
                            + (p << 2) + e], v);
        }
  }
}

// ---- pass 2: recompute, normalize, W_post in-register, PV with v[g2] -------
__global__ __launch_bounds__(256, 3)
void attn_pv2(const unsigned short* __restrict__ qb, const unsigned short* __restrict__ kall,
              const unsigned short* __restrict__ vallT, const float* __restrict__ W_pre,
              const float* __restrict__ W_post, const float* __restrict__ Lbuf,
              float* __restrict__ Obuf)
{
  __shared__ unsigned short sE[16 * 16 * 76];   // bf16 p2 [g2][i][k 0..63 +12]
  __shared__ f32x4 sWpre4[64], sWpost4[64];
  __shared__ float sIL[256];

  const int t = threadIdx.x, lane = t & 63, w = t >> 6;
  const int m = lane & 15, quad = lane >> 4;
  if (t < 64) {
    int h = t >> 2, p4 = t & 3;
    sWpre4[t]  = (f32x4){W_pre[(4 * p4 + 0) * 16 + h],  W_pre[(4 * p4 + 1) * 16 + h],
                         W_pre[(4 * p4 + 2) * 16 + h],  W_pre[(4 * p4 + 3) * 16 + h]};
    sWpost4[t] = (f32x4){W_post[(4 * p4 + 0) * 16 + h], W_post[(4 * p4 + 1) * 16 + h],
                         W_post[(4 * p4 + 2) * 16 + h], W_post[(4 * p4 + 3) * 16 + h]};
  }
  __syncthreads();

  int u = 5 * blockIdx.x;          // grid 448, 5 macro-units each
  const int u1 = u + 5;

  int accu = 0, bi = 0;
  while (true) {
    int un = ((bi & 63) + 5) >> 2;
    if (accu + un > u) break;
    accu += un; ++bi;
  }
  int b = bi >> 6, it = bi & 63, uoff = u - accu;

  f32x4 oacc[4][4];
  bool fresh = true;

  for (; u < u1; ++u) {
    const int i0 = it << 4;
    if (fresh) {
#pragma unroll
      for (int a = 0; a < 4; ++a)
#pragma unroll
        for (int dt = 0; dt < 4; ++dt) oacc[a][dt] = (f32x4){0.f, 0.f, 0.f, 0.f};
      sIL[t] = 1.f / Lbuf[(((size_t)(b << 10) + i0 + (t >> 4)) << 4) + (t & 15)];
      fresh = false;
      __syncthreads();             // sIL visible to all waves (block-uniform)
    }
    const int j0 = uoff << 6;
    const int js = j0 + (w << 4);
    const int jj = min(js + m, 1055);
    const unsigned short* qrow = qb + (((size_t)((b << 10) + i0 + m)) << 10);
    const unsigned short* krow = kall + (((size_t)(b * 1056 + jj)) << 10);

    // ---- QK all 16 heads with in-register W_pre premix ----
    f32x4 ap[4][4];                // [reg][p], components = e
#pragma unroll
    for (int r = 0; r < 4; ++r)
#pragma unroll
      for (int p = 0; p < 4; ++p) ap[r][p] = (f32x4){0.f, 0.f, 0.f, 0.f};
#pragma unroll
    for (int h = 0; h < 16; ++h) {
      short8 q0 = *(const short8*)(qrow + h * 64 + quad * 8);
      short8 q1 = *(const short8*)(qrow + h * 64 + 32 + quad * 8);
      short8 k0 = *(const short8*)(krow + h * 64 + quad * 8);
      short8 k1 = *(const short8*)(krow + h * 64 + 32 + quad * 8);
      f32x4 acc = (f32x4){0.f, 0.f, 0.f, 0.f};
      acc = __builtin_amdgcn_mfma_f32_16x16x32_bf16(q0, k0, acc, 0, 0, 0);
      acc = __builtin_amdgcn_mfma_f32_16x16x32_bf16(q1, k1, acc, 0, 0, 0);
#pragma unroll
      for (int p = 0; p < 4; ++p) {
        f32x4 wv = sWpre4[(h << 2) + p];
#pragma unroll
        for (int r = 0; r < 4; ++r) ap[r][p] += wv * acc[r];
      }
    }
    // ---- mask + exp + normalize (in place) ----
#pragma unroll
    for (int r = 0; r < 4; ++r) {
      const int iL = (quad << 2) + r;
      const bool ok = (js + m) <= (i0 + iL + 16);
#pragma unroll
      for (int p = 0; p < 4; ++p)
#pragma unroll
        for (int e = 0; e < 4; ++e) {
          float il = sIL[(iL << 4) + (p << 2) + e];
          ap[r][p][e] = ok ? __expf(ap[r][p][e] - 20.f) * il : 0.f;
        }
    }
    // ---- W_post postmix (quarter-wise) + write p2 -> sE ----
#pragma unroll
    for (int q = 0; q < 4; ++q) {
      f32x4 bp[4];                 // [reg], components = e2 (g2 = 4q+e2)
#pragma unroll
      for (int r = 0; r < 4; ++r) bp[r] = (f32x4){0.f, 0.f, 0.f, 0.f};
#pragma unroll
      for (int g = 0; g < 16; ++g) {
        f32x4 wv = sWpost4[(g << 2) + q];
#pragma unroll
        for (int r = 0; r < 4; ++r) bp[r] += wv * ap[r][g >> 2][g & 3];
      }
#pragma unroll
      for (int r = 0; r < 4; ++r) {
        const int iL = (quad << 2) + r;
#pragma unroll
        for (int e2 = 0; e2 < 4; ++e2)
          sE[(((q << 2) + e2) * 16 + iL) * 76 + (w << 4) + m] = to_bf(bp[r][e2]);
      }
    }
    __syncthreads();
    // ---- PV over K=64: wave w owns g2 = 4w..4w+3, V indexed by g2 ----
#pragma unroll
    for (int gl = 0; gl < 4; ++gl) {
      const int g2 = (w << 2) + gl;
      short8 a0 = *(const short8*)(sE + (g2 * 16 + m) * 76 + quad * 8);
      short8 a1 = *(const short8*)(sE + (g2 * 16 + m) * 76 + 32 + quad * 8);
#pragma unroll
      for (int dt = 0; dt < 4; ++dt) {
        const size_t vrow = ((size_t)((b << 10) + g2 * 64 + dt * 16 + m)) * 1056;
        const int c0 = min(j0 + quad * 8, 1048);
        const int c1 = min(j0 + 32 + quad * 8, 1048);
        short8 v0 = *(const short8*)(vallT + vrow + c0);
        short8 v1 = *(const short8*)(vallT + vrow + c1);
        oacc[gl][dt] = __builtin_amdgcn_mfma_f32_16x16x32_bf16(a0, v0, oacc[gl][dt], 0, 0, 0);
        oacc[gl][dt] = __builtin_amdgcn_mfma_f32_16x16x32_bf16(a1, v1, oacc[gl][dt], 0, 0, 0);
      }
    }
    __syncthreads();               // sE reused next macro-unit
    ++uoff;
    if (uoff == ((it + 5) >> 2)) {
#pragma unroll
      for (int gl = 0; gl < 4; ++gl) {
        int g2 = (w << 2) + gl;
#pragma unroll
        for (int dt = 0; dt < 4; ++dt)
#pragma unroll
          for (int reg = 0; reg < 4; ++reg)
            atomicAdd(&Obuf[(((size_t)(b << 10) + i0 + (quad << 2) + reg) << 10)
                            + g2 * 64 + dt * 16 + m], oacc[gl][dt][reg]);
      }
      ++bi; b = bi >> 6; it = bi & 63; uoff = 0; fresh = true;
    }
  }
  if (!fresh) {
    const int i0 = it << 4;
#pragma unroll
    for (int gl = 0; gl < 4; ++gl) {
      int g2 = (w << 2) + gl;
#pragma unroll
      for (int dt = 0; dt < 4; ++dt)
#pragma unroll
        for (int reg = 0; reg < 4; ++reg)
          atomicAdd(&Obuf[(((size_t)(b << 10) + i0 + (quad << 2) + reg) << 10)
                          + g2 * 64 + dt * 16 + m], oacc[gl][dt][reg]);
    }
  }
}

// ---- epilogue: aob = Obuf * hgate * vgate (bf16) ---------------------------
__global__ __launch_bounds__(256)
void gate_out(const float* __restrict__ Obuf, const float* __restrict__ hgate,
              const float* __restrict__ vgate, unsigned short* __restrict__ aob)
{
  int i4 = blockIdx.x * 256 + threadIdx.x;   // 1048576 float4 groups
  float4 o = ((const float4*)Obuf)[i4];
  int base = i4 << 2;
  int row = base >> 10, hd = base & 1023, h = hd >> 6;
  float hg = hgate[(row << 4) + h];
  float4 vg = ((const float4*)vgate)[i4];
  ushort4 r;
  r.x = to_bf(o.x * hg * vg.x);
  r.y = to_bf(o.y * hg * vg.y);
  r.z = to_bf(o.z * hg * vg.z);
  r.w = to_bf(o.w * hg * vg.w);
  ((ushort4*)aob)[i4] = r;
}

extern "C" void kernel_launch(void* const* d_in, const int* in_sizes, int n_in,
                              void* d_out, int out_size, void* d_ws, size_t ws_size,
                              hipStream_t stream)
{
  const float* x       = (const float*)d_in[0];
  const float* freqs   = (const float*)d_in[1];
  const float* Wq      = (const float*)d_in[2];
  const float* Wk      = (const float*)d_in[3];
  const float* Wv      = (const float*)d_in[4];
  const float* q_scale = (const float*)d_in[5];
  const float* k_scale = (const float*)d_in[6];
  const float* mem_k   = (const float*)d_in[7];
  const float* mem_v   = (const float*)d_in[8];
  const float* W_pre   = (const float*)d_in[9];
  const float* W_post  = (const float*)d_in[10];
  const float* W_hg    = (const float*)d_in[11];
  const float* b_hg    = (const float*)d_in[12];
  const float* W_vg    = (const float*)d_in[13];
  const float* b_vg    = (const float*)d_in[14];
  const float* Wo      = (const float*)d_in[15];
  float* out = (float*)d_out;
  float* ws  = (float*)d_ws;

  // workspace (float offsets), non-overlapping; total 19,660,800 f = 78.6 MiB
  float* q_lin = ws;                                        // [4096,1024]; dead -> aob+Lbuf
  unsigned short* aob = (unsigned short*)ws;                // bf16 alias
  float* Lbuf  = ws + 4128768;                              // [4,1024,16] (q_lin tail)
  float* k_lin = ws + 4194304;                              // [4096,1024]; dead -> Obuf
  float* Obuf  = k_lin;                                     // [4,1024,16,64] fp32
  float* vgbuf = ws + 8388608;                              // [4096,1024]
  float* hgbuf = ws + 12582912;                             // [4096,16]
  unsigned short* xb   = (unsigned short*)(ws + 12713984);  // [4096,1024] bf16 -> qb
  unsigned short* qb   = xb;                                // ends 14,811,136
  unsigned short* kall = (unsigned short*)(ws + 14811136);  // [4,1056,1024] bf16; ends 16,973,824
  unsigned short* vallT= (unsigned short*)(ws + 16973824);  // [4,1024,1056] bf16; ends 19,136,512
  unsigned short* wb   = (unsigned short*)(ws + 19136512);  // [1024,1024] bf16 (reused)

  dim3 blk(256);
  cvt_bf16x4<<<4096, blk, 0, stream>>>(x, xb, 1048576);
  // fused head-gate projection (fp32, reads original x)
  hgate_proj<<<256, blk, 0, stream>>>(x, W_hg, b_hg, hgbuf);
  // MFMA projections, 128x128 tiles (weight transpose buffer reused serially)
  transpose_to_bf<<<dim3(16, 16), blk, 0, stream>>>(Wq, wb);
  gemm_bf128<<<dim3(8, 32), blk, 0, stream>>>(xb, wb, q_lin, nullptr, nullptr, 0);
  transpose_to_bf<<<dim3(16, 16), blk, 0, stream>>>(Wk, wb);
  gemm_bf128<<<dim3(8, 32), blk, 0, stream>>>(xb, wb, k_lin, nullptr, nullptr, 0);
  transpose_to_bf<<<dim3(16, 16), blk, 0, stream>>>(Wv, wb);
  gemm_bf128<<<dim3(8, 32), blk, 0, stream>>>(xb, wb, nullptr, vallT, nullptr, 1);
  transpose_to_bf<<<dim3(16, 16), blk, 0, stream>>>(W_vg, wb);
  gemm_bf128<<<dim3(8, 32), blk, 0, stream>>>(xb, wb, vgbuf, nullptr, b_vg, 2);  // fused sigmoid
  // q/k/mem postprocessing (qb overwrites xb -- all xb readers done)
  q_post_bf<<<16384, blk, 0, stream>>>(q_lin, q_scale, freqs, qb);
  k_post_bf<<<16384, blk, 0, stream>>>(k_lin, k_scale, freqs, kall);
  mem_build<<<64, blk, 0, stream>>>(mem_k, mem_v, k_scale, kall, vallT);
  // zero Lbuf+Obuf in ONE contiguous memset (q_lin/k_lin dead by now)
  hipMemsetAsync(Lbuf, 0, (65536 + 4194304) * sizeof(float), stream);
  // two-pass attention + gate epilogue
  attn_lsum<<<1120, blk, 0, stream>>>(qb, kall, W_pre, Lbuf);
  attn_pv2<<<448, blk, 0, stream>>>(qb, kall, vallT, W_pre, W_post, Lbuf, Obuf);
  gate_out<<<4096, blk, 0, stream>>>(Obuf, hgbuf, vgbuf, aob);
  // output projection
  transpose_to_bf<<<dim3(16, 16), blk, 0, stream>>>(Wo, wb);
  gemm_bf128<<<dim3(8, 32), blk, 0, stream>>>(aob, wb, out, nullptr, nullptr, 0);
}